// Round 10
// baseline (580.781 us; speedup 1.0000x reference)
//
#include <hip/hip_runtime.h>

#define N_NODES 50000
#define N_EDGES 800000
#define NE4 (N_EDGES / 4)
#define NMASKW 1568          // ceil(50000/32)=1563, padded
#define MAXN1 192            // layer-2 LDS accumulator rows (deg(node1)~Poisson(16))
#define MAXDEG 1024          // per-node in-degree cap in layer12
#define NB 256               // blocks == CUs -> guaranteed co-resident
#define NT 512               // 8 waves/block
#define SLOTS 32             // slot stride in ints (128 B) -> no line sharing

__device__ __forceinline__ float lrelu(float v) { return v >= 0.f ? v : 0.01f * v; }
__device__ __forceinline__ bool mtest(const unsigned int* m, int i) {
    return (m[i >> 5] >> (i & 31)) & 1u;
}
__device__ __forceinline__ int aload(int* p) {
    return __hip_atomic_load(p, __ATOMIC_ACQUIRE, __HIP_MEMORY_SCOPE_AGENT);
}

struct WS {
    unsigned int *f1m, *f2m, *f3m;
    float *agg0, *t2;
    int *cntE1, *cntD, *cntC, *cnt1, *cnt2;
    int *e1src; int2 *eD; int2 *eC;
    int *list1, *pos1, *list2;
    int *slots;              // NB*SLOTS ints, 128B-strided; poison (<0) = pre-epoch
    int *flag;               // epoch flag; same poison trick
};

__global__ __launch_bounds__(NT) void gcn_mono(
    const float* __restrict__ x, const int4* __restrict__ src4,
    const int4* __restrict__ dst4,
    const float* __restrict__ W0, const float* __restrict__ b0,
    const float* __restrict__ W1, const float* __restrict__ b1,
    const float* __restrict__ W2, const float* __restrict__ b2,
    const float* __restrict__ W3, const float* __restrict__ b3,
    float* __restrict__ out, WS w)
{
    __shared__ union U {
        unsigned int m[NMASKW];                                      // scan phases
        struct { float xs[MAXDEG]; float rowA[64]; float rowH[128]; } l12;
        struct { float acc[MAXN1 * 64]; float t3s[MAXN1]; } tail;    // 48.8 KB
    } sh;
    __shared__ int nxs;

    const int tid  = threadIdx.x;
    const int gtid = blockIdx.x * NT + tid;
    const int gs   = NB * NT;

    // Grid barrier: padded-slot release-store arrival; block0 wave0 polls slots
    // with LOAD-ONLY coherent reads, publishes epoch flag; others poll flag
    // with one load-only reader. No RMW in the hot path.
    auto gbar = [&](int k) {
        __syncthreads();
        if (tid == 0) {
            __threadfence();
            __hip_atomic_store(&w.slots[blockIdx.x * SLOTS], k,
                               __ATOMIC_RELEASE, __HIP_MEMORY_SCOPE_AGENT);
        }
        if (blockIdx.x == 0) {
            if (tid < 64)
                for (int s = tid; s < NB; s += 64)
                    while (aload(&w.slots[s * SLOTS]) < k) __builtin_amdgcn_s_sleep(4);
            __syncthreads();
            if (tid == 0)
                __hip_atomic_store(w.flag, k, __ATOMIC_RELEASE, __HIP_MEMORY_SCOPE_AGENT);
        } else {
            if (tid == 0)
                while (aload(w.flag) < k) __builtin_amdgcn_s_sleep(4);
        }
        __syncthreads();
        __threadfence();
    };

    // ---- P0: zero masks / agg0 / counters ----
    for (int i = gtid; i < NMASKW; i += gs) { w.f1m[i] = 0; w.f2m[i] = 0; w.f3m[i] = 0; }
    for (int i = gtid; i < N_NODES; i += gs) w.agg0[i] = 0.f;
    if (gtid == 0) { *w.cntE1 = 0; *w.cntD = 0; *w.cntC = 0; *w.cnt1 = 0; *w.cnt2 = 0; }
    gbar(1);

    // ---- P1: edges with dst==1 -> f1 bits + e1src list ----
    for (int t = gtid; t < NE4; t += gs) {
        int4 d = dst4[t];
        if (d.x == 1 || d.y == 1 || d.z == 1 || d.w == 1) {
            int4 s = src4[t];
            if (d.x == 1) { atomicOr(&w.f1m[s.x >> 5], 1u << (s.x & 31)); w.e1src[atomicAdd(w.cntE1, 1)] = s.x; }
            if (d.y == 1) { atomicOr(&w.f1m[s.y >> 5], 1u << (s.y & 31)); w.e1src[atomicAdd(w.cntE1, 1)] = s.y; }
            if (d.z == 1) { atomicOr(&w.f1m[s.z >> 5], 1u << (s.z & 31)); w.e1src[atomicAdd(w.cntE1, 1)] = s.z; }
            if (d.w == 1) { atomicOr(&w.f1m[s.w >> 5], 1u << (s.w & 31)); w.e1src[atomicAdd(w.cntE1, 1)] = s.w; }
        }
    }
    gbar(2);

    // ---- P2: edges with f1[dst] -> f2 bits + eD list (f1 staged in LDS) ----
    for (int i = tid; i < NMASKW; i += NT) sh.m[i] = w.f1m[i];
    __syncthreads();
    for (int t = gtid; t < NE4; t += gs) {
        int4 d = dst4[t];
        bool ax = mtest(sh.m, d.x), ay = mtest(sh.m, d.y), az = mtest(sh.m, d.z), aw = mtest(sh.m, d.w);
        if (ax | ay | az | aw) {
            int4 s = src4[t];
            if (ax) { atomicOr(&w.f2m[s.x >> 5], 1u << (s.x & 31)); w.eD[atomicAdd(w.cntD, 1)] = make_int2(s.x, d.x); }
            if (ay) { atomicOr(&w.f2m[s.y >> 5], 1u << (s.y & 31)); w.eD[atomicAdd(w.cntD, 1)] = make_int2(s.y, d.y); }
            if (az) { atomicOr(&w.f2m[s.z >> 5], 1u << (s.z & 31)); w.eD[atomicAdd(w.cntD, 1)] = make_int2(s.z, d.z); }
            if (aw) { atomicOr(&w.f2m[s.w >> 5], 1u << (s.w & 31)); w.eD[atomicAdd(w.cntD, 1)] = make_int2(s.w, d.w); }
        }
    }
    gbar(3);

    // ---- P3: edges with f2[dst] -> f3 bits + eC list; node compaction ----
    for (int i = tid; i < NMASKW; i += NT) sh.m[i] = w.f2m[i];
    __syncthreads();
    for (int t = gtid; t < NE4; t += gs) {
        int4 d = dst4[t];
        bool ax = mtest(sh.m, d.x), ay = mtest(sh.m, d.y), az = mtest(sh.m, d.z), aw = mtest(sh.m, d.w);
        if (ax | ay | az | aw) {
            int4 s = src4[t];
            if (ax) { atomicOr(&w.f3m[s.x >> 5], 1u << (s.x & 31)); w.eC[atomicAdd(w.cntC, 1)] = make_int2(s.x, d.x); }
            if (ay) { atomicOr(&w.f3m[s.y >> 5], 1u << (s.y & 31)); w.eC[atomicAdd(w.cntC, 1)] = make_int2(s.y, d.y); }
            if (az) { atomicOr(&w.f3m[s.z >> 5], 1u << (s.z & 31)); w.eC[atomicAdd(w.cntC, 1)] = make_int2(s.z, d.z); }
            if (aw) { atomicOr(&w.f3m[s.w >> 5], 1u << (s.w & 31)); w.eC[atomicAdd(w.cntC, 1)] = make_int2(s.w, d.w); }
        }
    }
    for (int i = gtid; i < N_NODES; i += gs) {
        if (mtest(w.f1m, i)) { int p = atomicAdd(w.cnt1, 1); if (p < MAXN1) w.list1[p] = i; w.pos1[i] = p; }
        if (mtest(w.f2m, i)) { w.list2[atomicAdd(w.cnt2, 1)] = i; }
    }
    gbar(4);

    // ---- P4: f3-filtered scalar aggregation: agg0[d] += x[s] (~65k atomics) ----
    for (int i = tid; i < NMASKW; i += NT) sh.m[i] = w.f3m[i];
    __syncthreads();
    for (int t = gtid; t < NE4; t += gs) {
        int4 d = dst4[t];
        bool ax = mtest(sh.m, d.x), ay = mtest(sh.m, d.y), az = mtest(sh.m, d.z), aw = mtest(sh.m, d.w);
        if (ax | ay | az | aw) {
            int4 s = src4[t];
            if (ax) atomicAdd(&w.agg0[d.x], x[s.x]);
            if (ay) atomicAdd(&w.agg0[d.y], x[s.y]);
            if (az) atomicAdd(&w.agg0[d.z], x[s.z]);
            if (aw) atomicAdd(&w.agg0[d.w], x[s.w]);
        }
    }
    gbar(5);

    // ---- P5: per N2-node: gather agg0 via eC, layer0 lin+lrelu+sum,
    //          h1 = lrelu(.@W1+b1), t2 = h1@W2 ----
    {
        int cC = aload(w.cntC), c2 = aload(w.cnt2);
        for (int idx = blockIdx.x; idx < c2; idx += NB) {
            int node = w.list2[idx];
            __syncthreads();
            if (tid == 0) nxs = 0;
            __syncthreads();
            for (int k = tid; k < cC; k += NT) {
                int2 e = w.eC[k];
                if (e.y == node) { int p = atomicAdd(&nxs, 1); if (p < MAXDEG) sh.l12.xs[p] = w.agg0[e.x]; }
            }
            __syncthreads();
            int deg = nxs < MAXDEG ? nxs : MAXDEG;
            if (tid < 64) {
                float wj = W0[tid], bj = b0[tid], s = 0.f;
                for (int k = 0; k < deg; ++k) s += lrelu(sh.l12.xs[k] * wj + bj);
                sh.l12.rowA[tid] = s;
            }
            __syncthreads();
            if (tid < 128) {
                float acc = b1[tid];
#pragma unroll
                for (int k = 0; k < 64; ++k) acc += sh.l12.rowA[k] * W1[k * 128 + tid];
                sh.l12.rowH[tid] = lrelu(acc);
            }
            __syncthreads();
            if (tid < 64) {
                float a2 = 0.f;
#pragma unroll
                for (int k = 0; k < 128; ++k) a2 += sh.l12.rowH[k] * W2[k * 64 + tid];
                w.t2[(size_t)node * 64 + tid] = a2;
            }
        }
    }
    gbar(6);

    // ---- tail (block 0 only): layer-2 agg into LDS, t3, final sum, output ----
    if (blockIdx.x == 0) {
        int c1 = aload(w.cnt1); if (c1 > MAXN1) c1 = MAXN1;
        int cD = aload(w.cntD), cE = aload(w.cntE1);
        for (int k = tid; k < c1 * 64; k += NT) sh.tail.acc[k] = 0.f;
        __syncthreads();
        int lane = tid & 63, wv = tid >> 6;              // 8 waves
        for (int idx = wv; idx < cD; idx += 8) {
            int2 e = w.eD[idx];
            int p = w.pos1[e.y];
            if (p < MAXN1) atomicAdd(&sh.tail.acc[p * 64 + lane], w.t2[(size_t)e.x * 64 + lane]);
        }
        __syncthreads();
        for (int slot = wv; slot < c1; slot += 8) {
            float v = lrelu(sh.tail.acc[slot * 64 + lane] + b2[lane]) * W3[lane];
            for (int o = 32; o > 0; o >>= 1) v += __shfl_down(v, o, 64);
            if (lane == 0) sh.tail.t3s[slot] = v;
        }
        __syncthreads();
        if (tid < 64) {
            float s = 0.f;
            for (int k = tid; k < cE; k += 64) s += sh.tail.t3s[w.pos1[w.e1src[k]]];
            for (int o = 32; o > 0; o >>= 1) s += __shfl_down(s, o, 64);
            if (tid == 0) out[0] = lrelu(s + b3[0]);
        }
    }
}

extern "C" void kernel_launch(void* const* d_in, const int* in_sizes, int n_in,
                              void* d_out, int out_size, void* d_ws, size_t ws_size,
                              hipStream_t stream) {
    const float* in_feat = (const float*)d_in[0];
    const int*   src     = (const int*)d_in[1];
    const int*   dst     = (const int*)d_in[2];
    const float* W0 = (const float*)d_in[3];  const float* b0 = (const float*)d_in[4];
    const float* W1 = (const float*)d_in[5];  const float* b1 = (const float*)d_in[6];
    const float* W2 = (const float*)d_in[7];  const float* b2 = (const float*)d_in[8];
    const float* W3 = (const float*)d_in[9];  const float* b3 = (const float*)d_in[10];
    float* out = (float*)d_out;

    char* base = (char*)d_ws;
    size_t off = 0;
    auto take = [&](size_t bytes) { char* p = base + off; off += (bytes + 255) & ~(size_t)255; return p; };

    WS w;
    w.f1m  = (unsigned int*)take(NMASKW * 4);
    w.f2m  = (unsigned int*)take(NMASKW * 4);
    w.f3m  = (unsigned int*)take(NMASKW * 4);
    w.agg0 = (float*)take((size_t)N_NODES * 4);
    w.t2   = (float*)take((size_t)N_NODES * 64 * 4);
    w.cntE1 = (int*)take(4); w.cntD = (int*)take(4); w.cntC = (int*)take(4);
    w.cnt1  = (int*)take(4); w.cnt2 = (int*)take(4);
    w.e1src = (int*)take((size_t)N_NODES * 4);
    w.eD    = (int2*)take((size_t)N_EDGES * 8);
    w.eC    = (int2*)take((size_t)N_EDGES * 8);
    w.list1 = (int*)take((size_t)N_NODES * 4);
    w.pos1  = (int*)take((size_t)N_NODES * 4);
    w.list2 = (int*)take((size_t)N_NODES * 4);
    w.slots = (int*)take((size_t)NB * SLOTS * 4);  // NOT zeroed: poison < any epoch
    w.flag  = (int*)take(4);                       // same

    gcn_mono<<<NB, NT, 0, stream>>>(in_feat, (const int4*)src, (const int4*)dst,
                                    W0, b0, W1, b1, W2, b2, W3, b3, out, w);
}

// Round 11
// 176.708 us; speedup vs baseline: 3.2867x; 3.2867x over previous
//
#include <hip/hip_runtime.h>

#define N_NODES 50000
#define N_EDGES 800000
#define NE4 (N_EDGES / 4)
#define NMASKW 1568          // ceil(50000/32)=1563, padded
#define MAXN1 192            // LDS accumulator rows in fusedD (deg(node1)~Poisson(16))
#define MAXDEG 1024          // per-node in-degree cap in layer12

__device__ __forceinline__ float lrelu(float v) { return v >= 0.f ? v : 0.01f * v; }
__device__ __forceinline__ bool mtest(const unsigned int* m, int i) {
    return (m[i >> 5] >> (i & 31)) & 1u;
}

// ---- scan1: edges with dst==1 -> f1 bits + e1src list ----
__global__ void scan1_k(const int4* __restrict__ dst4, const int* __restrict__ src,
                        unsigned int* __restrict__ f1m, int* __restrict__ e1src,
                        int* __restrict__ cntE1) {
    int t = blockIdx.x * blockDim.x + threadIdx.x;
    if (t >= NE4) return;
    int4 d = dst4[t];
    int base = t * 4;
    if (d.x == 1) { int s = src[base + 0]; atomicOr(&f1m[s >> 5], 1u << (s & 31)); e1src[atomicAdd(cntE1, 1)] = s; }
    if (d.y == 1) { int s = src[base + 1]; atomicOr(&f1m[s >> 5], 1u << (s & 31)); e1src[atomicAdd(cntE1, 1)] = s; }
    if (d.z == 1) { int s = src[base + 2]; atomicOr(&f1m[s >> 5], 1u << (s & 31)); e1src[atomicAdd(cntE1, 1)] = s; }
    if (d.w == 1) { int s = src[base + 3]; atomicOr(&f1m[s >> 5], 1u << (s & 31)); e1src[atomicAdd(cntE1, 1)] = s; }
}

// ---- scan2: edges with f1[dst] -> eD list + f2 bits (f1 mask staged in LDS) ----
__global__ void scan2_k(const int4* __restrict__ dst4, const int* __restrict__ src,
                        const unsigned int* __restrict__ f1m, unsigned int* __restrict__ f2m,
                        int2* __restrict__ eD, int* __restrict__ cntD) {
    __shared__ unsigned int m[NMASKW];
    for (int k = threadIdx.x; k < NMASKW; k += blockDim.x) m[k] = f1m[k];
    __syncthreads();
    int t = blockIdx.x * blockDim.x + threadIdx.x;
    if (t >= NE4) return;
    int4 d = dst4[t];
    int base = t * 4;
#define DO_E(dd, off) \
    if (mtest(m, dd)) { int s = src[base + off]; atomicOr(&f2m[s >> 5], 1u << (s & 31)); \
                        eD[atomicAdd(cntD, 1)] = make_int2(s, dd); }
    DO_E(d.x, 0) DO_E(d.y, 1) DO_E(d.z, 2) DO_E(d.w, 3)
#undef DO_E
}

// ---- scan3 + compact fused: edges with f2[dst] -> eC list + f3 bits;
//      nodes: cnt1/pos1 (f1), list2 (f2) ----
__global__ void scan3_k(const int4* __restrict__ dst4, const int* __restrict__ src,
                        const unsigned int* __restrict__ f1m, const unsigned int* __restrict__ f2m,
                        unsigned int* __restrict__ f3m,
                        int2* __restrict__ eC, int* __restrict__ cntC,
                        int* __restrict__ cnt1, int* __restrict__ pos1,
                        int* __restrict__ list2, int* __restrict__ cnt2) {
    __shared__ unsigned int m1[NMASKW];
    __shared__ unsigned int m2[NMASKW];
    for (int k = threadIdx.x; k < NMASKW; k += blockDim.x) { m1[k] = f1m[k]; m2[k] = f2m[k]; }
    __syncthreads();
    int t = blockIdx.x * blockDim.x + threadIdx.x;
    if (t < NE4) {
        int4 d = dst4[t];
        int base = t * 4;
#define DO_E(dd, off) \
        if (mtest(m2, dd)) { int s = src[base + off]; atomicOr(&f3m[s >> 5], 1u << (s & 31)); \
                             eC[atomicAdd(cntC, 1)] = make_int2(s, dd); }
        DO_E(d.x, 0) DO_E(d.y, 1) DO_E(d.z, 2) DO_E(d.w, 3)
#undef DO_E
    }
    if (t < N_NODES) {
        if (mtest(m1, t)) { int p = atomicAdd(cnt1, 1); pos1[t] = p; }
        if (mtest(m2, t)) { list2[atomicAdd(cnt2, 1)] = t; }
    }
}

// ---- scan4: edges with f3[dst] -> agg0[d] += x[s] (~65k atomics) ----
__global__ void scan4_k(const int4* __restrict__ dst4, const int* __restrict__ src,
                        const float* __restrict__ x, const unsigned int* __restrict__ f3m,
                        float* __restrict__ agg0) {
    __shared__ unsigned int m[NMASKW];
    for (int k = threadIdx.x; k < NMASKW; k += blockDim.x) m[k] = f3m[k];
    __syncthreads();
    int t = blockIdx.x * blockDim.x + threadIdx.x;
    if (t >= NE4) return;
    int4 d = dst4[t];
    int base = t * 4;
    if (mtest(m, d.x)) atomicAdd(&agg0[d.x], x[src[base + 0]]);
    if (mtest(m, d.y)) atomicAdd(&agg0[d.y], x[src[base + 1]]);
    if (mtest(m, d.z)) atomicAdd(&agg0[d.z], x[src[base + 2]]);
    if (mtest(m, d.w)) atomicAdd(&agg0[d.w], x[src[base + 3]]);
}

// ---- layer12: per N2-node block: gather in-edge agg0 from eC, layer0 lin+lrelu+sum,
//      h1 = lrelu(.@W1+b1), t2 = h1@W2 (weights from global/L2) ----
__global__ __launch_bounds__(128) void layer12_k(const int2* __restrict__ eC,
                                                 const int* __restrict__ cntC,
                                                 const float* __restrict__ agg0,
                                                 const int* __restrict__ list2,
                                                 const int* __restrict__ cnt2,
                                                 const float* __restrict__ W0,
                                                 const float* __restrict__ b0,
                                                 const float* __restrict__ W1,
                                                 const float* __restrict__ b1,
                                                 const float* __restrict__ W2,
                                                 float* __restrict__ t2) {
    __shared__ float xs[MAXDEG];
    __shared__ int nxs;
    __shared__ float rowA[64];
    __shared__ float rowH[128];
    int tid = threadIdx.x;
    int cC = *cntC, c2 = *cnt2;
    for (int idx = blockIdx.x; idx < c2; idx += gridDim.x) {
        int node = list2[idx];
        __syncthreads();                      // protect xs/nxs/rowA/rowH reuse
        if (tid == 0) nxs = 0;
        __syncthreads();
        for (int k = tid; k < cC; k += 128) {
            int2 e = eC[k];
            if (e.y == node) {
                int p = atomicAdd(&nxs, 1);
                if (p < MAXDEG) xs[p] = agg0[e.x];
            }
        }
        __syncthreads();
        int deg = nxs < MAXDEG ? nxs : MAXDEG;
        if (tid < 64) {
            float w = W0[tid], b = b0[tid], s = 0.f;
            for (int k = 0; k < deg; ++k) s += lrelu(xs[k] * w + b);
            rowA[tid] = s;
        }
        __syncthreads();
        float acc = b1[tid];
#pragma unroll
        for (int k = 0; k < 64; ++k) acc += rowA[k] * W1[k * 128 + tid];
        rowH[tid] = lrelu(acc);
        __syncthreads();
        if (tid < 64) {
            float a2 = 0.f;
#pragma unroll
            for (int k = 0; k < 128; ++k) a2 += rowH[k] * W2[k * 64 + tid];
            t2[(size_t)node * 64 + tid] = a2;
        }
    }
}

// ---- fusedD: layer-2 agg (LDS acc over eD) + layer-3 linear + final sum, 1 block ----
__global__ __launch_bounds__(256) void fusedD_k(const int2* __restrict__ eD, const int* __restrict__ cntD,
                                                const float* __restrict__ t2, const int* __restrict__ pos1,
                                                const int* __restrict__ cnt1, const int* __restrict__ e1src,
                                                const int* __restrict__ cntE1, const float* __restrict__ b2,
                                                const float* __restrict__ W3, const float* __restrict__ b3,
                                                float* __restrict__ out) {
    __shared__ float acc[MAXN1 * 64];   // 48 KB
    __shared__ float t3s[MAXN1];
    int tid = threadIdx.x;
    int c1 = *cnt1; if (c1 > MAXN1) c1 = MAXN1;
    int cD = *cntD, cE = *cntE1;
    for (int k = tid; k < c1 * 64; k += 256) acc[k] = 0.f;
    __syncthreads();
    int j = tid & 63, widx = tid >> 6;           // 4 waves
    for (int idx = widx; idx < cD; idx += 4) {
        int2 e = eD[idx];
        int p = pos1[e.y];
        if (p < MAXN1) atomicAdd(&acc[p * 64 + j], t2[(size_t)e.x * 64 + j]);
    }
    __syncthreads();
    for (int slot = widx; slot < c1; slot += 4) {
        float v = lrelu(acc[slot * 64 + j] + b2[j]) * W3[j];
        for (int off = 32; off > 0; off >>= 1) v += __shfl_down(v, off, 64);
        if (j == 0) t3s[slot] = v;
    }
    __syncthreads();
    if (tid < 64) {
        float s = 0.f;
        for (int k = tid; k < cE; k += 64) s += t3s[pos1[e1src[k]]];
        for (int off = 32; off > 0; off >>= 1) s += __shfl_down(s, off, 64);
        if (tid == 0) out[0] = lrelu(s + b3[0]);
    }
}

extern "C" void kernel_launch(void* const* d_in, const int* in_sizes, int n_in,
                              void* d_out, int out_size, void* d_ws, size_t ws_size,
                              hipStream_t stream) {
    const float* in_feat = (const float*)d_in[0];
    const int*   src     = (const int*)d_in[1];
    const int*   dst     = (const int*)d_in[2];
    const float* W0 = (const float*)d_in[3];  const float* b0 = (const float*)d_in[4];
    const float* W1 = (const float*)d_in[5];  const float* b1 = (const float*)d_in[6];
    const float* W2 = (const float*)d_in[7];  const float* b2 = (const float*)d_in[8];
    const float* W3 = (const float*)d_in[9];  const float* b3 = (const float*)d_in[10];
    float* out = (float*)d_out;
    const int4* dst4 = (const int4*)dst;

    // ---- workspace: zeroed prefix first ----
    char* base = (char*)d_ws;
    size_t off = 0;
    auto take = [&](size_t bytes) { char* p = base + off; off += (bytes + 255) & ~(size_t)255; return p; };
    unsigned int* f1m = (unsigned int*)take(NMASKW * 4);      // zeroed
    unsigned int* f2m = (unsigned int*)take(NMASKW * 4);      // zeroed
    unsigned int* f3m = (unsigned int*)take(NMASKW * 4);      // zeroed
    int* cntE1 = (int*)take(4);                               // zeroed
    int* cntD  = (int*)take(4);                               // zeroed
    int* cntC  = (int*)take(4);                               // zeroed
    int* cnt1  = (int*)take(4);                               // zeroed
    int* cnt2  = (int*)take(4);                               // zeroed
    float* agg0 = (float*)take((size_t)N_NODES * 4);          // zeroed
    size_t zero_bytes = off;
    float* t2   = (float*)take((size_t)N_NODES * 64 * 4);
    int*  e1src = (int*)take((size_t)N_NODES * 4);
    int2* eD    = (int2*)take((size_t)N_EDGES * 8);
    int2* eC    = (int2*)take((size_t)N_EDGES * 8);
    int*  list2 = (int*)take((size_t)N_NODES * 4);
    int*  pos1  = (int*)take((size_t)N_NODES * 4);

    const int SB = (NE4 + 255) / 256;   // 782 blocks

    hipMemsetAsync(base, 0, zero_bytes, stream);                                   // ~220 KB
    scan1_k<<<SB, 256, 0, stream>>>(dst4, src, f1m, e1src, cntE1);                 // f1 + e1 edges
    scan2_k<<<SB, 256, 0, stream>>>(dst4, src, f1m, f2m, eD, cntD);                // f2 + eD
    scan3_k<<<SB, 256, 0, stream>>>(dst4, src, f1m, f2m, f3m, eC, cntC,
                                    cnt1, pos1, list2, cnt2);                      // f3 + eC + lists
    scan4_k<<<SB, 256, 0, stream>>>(dst4, src, in_feat, f3m, agg0);                // agg0 (f3-filtered)
    layer12_k<<<256, 128, 0, stream>>>(eC, cntC, agg0, list2, cnt2,
                                       W0, b0, W1, b1, W2, t2);                    // layers 0-2 linear
    fusedD_k<<<1, 256, 0, stream>>>(eD, cntD, t2, pos1, cnt1, e1src, cntE1,
                                    b2, W3, b3, out);                              // tail
}